// Round 6
// baseline (3005.702 us; speedup 1.0000x reference)
//
#include <hip/hip_runtime.h>
#include <hip/hip_bf16.h>
#include <stdint.h>
#include <stddef.h>

typedef _Float16 f16;
typedef __attribute__((ext_vector_type(8))) _Float16 f16x8;
typedef __attribute__((ext_vector_type(4))) _Float16 f16x4;
typedef __attribute__((ext_vector_type(4))) float f32x4;
typedef __attribute__((ext_vector_type(4))) uint32_t u32x4;
typedef __attribute__((ext_vector_type(2))) uint32_t u32x2;

// Problem constants
#define T_STEPS 512
#define BATCH   64
#define KDIM    1024     // I == H == 1024
#define NGATE   3072     // 3*H

// Workspace layout (bytes), all 256-aligned
#define OFF_XF16   0L            // x as f16
#define OFF_WIH    67108864L     // w_ih f16
#define OFF_WHH    73400320L     // w_hh f16
#define OFF_XPROJ  79691776L     // x_proj f16: 32768*3072*2
#define OFF_HA     281018368L    // h f16 ping-pong, A-FRAGMENT layout: 2*131072 B
#define OFF_BAR    281280512L    // 256 per-wave flag dwords

__device__ __forceinline__ void gload_lds16(const void* g, void* l) {
    __builtin_amdgcn_global_load_lds((__attribute__((address_space(1))) void*)g,
                                     (__attribute__((address_space(3))) void*)l,
                                     16, 0, 0);
}

// fragment index of h element (row, col):
//   chunk = ((row>>4)*32 + (col>>5))*64 + ((col>>3)&3)*16 + (row&15), elem = col&7
__device__ __forceinline__ int frag_idx(int row, int col) {
    return ((((row >> 4) * 32 + (col >> 5)) * 64 + ((col >> 3) & 3) * 16 + (row & 15)) << 3)
           + (col & 7);
}

// fast activations: v_exp/v_rcp based, endpoint-safe
__device__ __forceinline__ float fast_sigmoid(float x) {
    return __builtin_amdgcn_rcpf(1.f + __expf(-x));
}
__device__ __forceinline__ float fast_tanh(float x) {
    return 1.f - 2.f * __builtin_amdgcn_rcpf(1.f + __expf(2.f * x));
}

// ---------------- prep kernels ----------------

__global__ void init_misc(const float* __restrict__ h0,
                          f16* __restrict__ hA, unsigned* __restrict__ bar) {
    if (blockIdx.x == 0) bar[threadIdx.x] = 0u;   // 256 per-wave flags
    int i = blockIdx.x * 256 + threadIdx.x;       // 256 blocks -> exactly 65536 threads
    int row = i >> 10, col = i & 1023;
    hA[frag_idx(row, col)] = (_Float16)h0[i];
}

__global__ void cvt_f16(const float* __restrict__ src, f16* __restrict__ dst, int n4) {
    int i = blockIdx.x * blockDim.x + threadIdx.x;
    int stride = gridDim.x * blockDim.x;
    for (; i < n4; i += stride) {
        float4 v = ((const float4*)src)[i];
        f16x4 o = { (_Float16)v.x, (_Float16)v.y, (_Float16)v.z, (_Float16)v.w };
        *(f16x4*)&dst[(size_t)i * 4] = o;
    }
}

// ---------------- x-projection GEMM ----------------

__global__ __launch_bounds__(256) void gemm_xproj(const f16* __restrict__ A,
                                                  const f16* __restrict__ Bt,
                                                  const float* __restrict__ bias,
                                                  f16* __restrict__ C) {
    __shared__ f16 As[128 * 32];
    __shared__ f16 Bs[128 * 32];
    const int K = KDIM;
    int bm = blockIdx.x / 24, bn = blockIdx.x % 24;
    int m0 = bm * 128, n0 = bn * 128;
    int tid = threadIdx.x, wave = tid >> 6, lane = tid & 63;
    int wm = wave >> 1, wn = wave & 1;

    f32x4 acc[4][4];
#pragma unroll
    for (int i = 0; i < 4; i++)
#pragma unroll
        for (int j = 0; j < 4; j++) acc[i][j] = (f32x4){0.f, 0.f, 0.f, 0.f};

    int srow = lane >> 2;
    int kc = lane & 3;

    for (int k0 = 0; k0 < K; k0 += 32) {
#pragma unroll
        for (int s = 0; s < 2; ++s) {
            int seg = wave * 2 + s;
            int row = seg * 16 + srow;
            gload_lds16(&A[(size_t)(m0 + row) * K + k0 + kc * 8], &As[seg * 512]);
            gload_lds16(&Bt[(size_t)(n0 + row) * K + k0 + kc * 8], &Bs[seg * 512]);
        }
        __syncthreads();

        f16x8 af[4], bfg[4];
#pragma unroll
        for (int i = 0; i < 4; i++) {
            af[i]  = *(const f16x8*)&As[(wm * 64 + i * 16 + (lane & 15)) * 32 + (lane >> 4) * 8];
            bfg[i] = *(const f16x8*)&Bs[(wn * 64 + i * 16 + (lane & 15)) * 32 + (lane >> 4) * 8];
        }
#pragma unroll
        for (int i = 0; i < 4; i++)
#pragma unroll
            for (int j = 0; j < 4; j++)
                acc[i][j] = __builtin_amdgcn_mfma_f32_16x16x32_f16(af[i], bfg[j], acc[i][j], 0, 0, 0);
        __syncthreads();
    }

#pragma unroll
    for (int j = 0; j < 4; j++) {
        int col = n0 + wn * 64 + j * 16 + (lane & 15);
        float bv = bias[col];
#pragma unroll
        for (int i = 0; i < 4; i++) {
            int rbase = m0 + wm * 64 + i * 16 + (lane >> 4) * 4;
#pragma unroll
            for (int r = 0; r < 4; r++)
                C[(size_t)(rbase + r) * NGATE + col] = (_Float16)(acc[i][j][r] + bv);
        }
    }
}

// ---------------- persistent GRU scan ----------------
// 64 blocks x 256 threads (1 block/CU). Block p owns hidden cols [16p, 16p+16).
// Per-wave producer path: gates -> LDS transpose (640B/wave, conflict-free)
// -> ONE contiguous global_store_dwordx2 per lane -> per-wave drain+flag
// (NO producer __syncthreads). Consumer: wave0 polls all 256 wave-flags with
// one dwordx4 load; h loads are 32 batched LLC loads with STAGED vmcnt waits
// so MFMA overlaps the load tail.

__global__ __launch_bounds__(256, 1) void gru_scan(const f16* __restrict__ xproj,
                                                   const f16* __restrict__ whh16,
                                                   const float* __restrict__ bhh,
                                                   const float* __restrict__ h0,
                                                   f16* __restrict__ hA,
                                                   float* __restrict__ out,
                                                   unsigned* __restrict__ flags) {
    __shared__ f16 Bsh[32 * 64 * 8];        // gate-n B-fragments, 32 KiB
    __shared__ uint32_t TL32[4][160];       // per-wave transpose scratch (640 B each)

    const int tid = threadIdx.x, wave = tid >> 6, lane = tid & 63;
    const int blk = blockIdx.x;
    const int j0 = blk * 16;
    const int col = lane & 15;
    const int kofs = (lane >> 4) * 8;

    // stage gate-n B-fragments into LDS
    for (int c = tid; c < 2048; c += 256) {
        int ks = c >> 6, l = c & 63;
        int row = 2048 + j0 + (l & 15);
        int kk = ks * 32 + ((l >> 4) * 8);
        *(f16x8*)&Bsh[c * 8] = *(const f16x8*)&whh16[(size_t)row * 1024 + kk];
    }

    // gates r,z B-fragments in registers
    f16x8 bw0[32], bw1[32];
#pragma unroll
    for (int ks = 0; ks < 32; ++ks) {
        bw0[ks] = *(const f16x8*)&whh16[(size_t)(j0 + col) * 1024 + ks * 32 + kofs];
        bw1[ks] = *(const f16x8*)&whh16[(size_t)(1024 + j0 + col) * 1024 + ks * 32 + kofs];
    }

    const float bh_r = bhh[j0 + col];
    const float bh_z = bhh[1024 + j0 + col];
    const float bh_n = bhh[2048 + j0 + col];

    const int brow = wave * 16 + ((lane >> 4) << 2);   // C/D row base
    float hp[4];
#pragma unroll
    for (int r = 0; r < 4; ++r) hp[r] = h0[(size_t)(brow + r) * 1024 + j0 + col];

    // producer store addressing: lane -> (row16 = lane>>2, qcol = lane&3)
    const int ksb = blk >> 1;
    const int lhb = (blk & 1) << 1;
    const int p_row16 = lane >> 2;
    const int p_qcol  = lane & 3;
    const int p_chunk = (wave * 32 + ksb) * 64 + (lhb + (p_qcol >> 1)) * 16 + p_row16;
    const long p_off  = (long)p_chunk * 16 + (p_qcol & 1) * 8;   // byte offset in buffer

    __syncthreads();

    // xproj prefetch for t=0
    float xr[4], xz[4], xn[4];
#pragma unroll
    for (int r = 0; r < 4; ++r) {
        size_t xb = ((size_t)0 * BATCH + brow + r) * NGATE + j0 + col;
        xr[r] = (float)__builtin_nontemporal_load(&xproj[xb]);
        xz[r] = (float)__builtin_nontemporal_load(&xproj[xb + 1024]);
        xn[r] = (float)__builtin_nontemporal_load(&xproj[xb + 2048]);
    }

    int cur = 0;
#pragma unroll 1
    for (int t = 0; t < T_STEPS; ++t) {
        // drain any leftover vmem (xproj prefetch, out stores) so vmcnt
        // counting below is exact
        asm volatile("s_waitcnt vmcnt(0)" ::: "memory");

        // ---- batched A-fragment loads (32 x 16B/lane, LLC-coherent) ----
        const char* hb = (const char*)hA + (size_t)cur * 131072
                       + (size_t)wave * 32768 + (size_t)lane * 16;
        f16x8 A[32];
#define HLOAD4(g4)                                                              \
        { const char* bp = hb + (g4) * 4096;                                    \
          asm volatile("global_load_dwordx4 %0, %4, off sc0 sc1\n\t"            \
                       "global_load_dwordx4 %1, %4, off offset:1024 sc0 sc1\n\t"\
                       "global_load_dwordx4 %2, %4, off offset:2048 sc0 sc1\n\t"\
                       "global_load_dwordx4 %3, %4, off offset:3072 sc0 sc1"    \
                       : "=&v"(A[(g4)*4]), "=&v"(A[(g4)*4+1]),                  \
                         "=&v"(A[(g4)*4+2]), "=&v"(A[(g4)*4+3])                 \
                       : "v"(bp)); }
        HLOAD4(0) HLOAD4(1) HLOAD4(2) HLOAD4(3)
        HLOAD4(4) HLOAD4(5) HLOAD4(6) HLOAD4(7)
#undef HLOAD4

        // ---- MFMA overlapped with load tail: staged vmcnt waits ----
        f32x4 acc0 = {0.f,0.f,0.f,0.f}, acc1 = {0.f,0.f,0.f,0.f}, acc2 = {0.f,0.f,0.f,0.f};

        asm volatile("s_waitcnt vmcnt(24)" ::: "memory");
        __builtin_amdgcn_sched_barrier(0);
#pragma unroll
        for (int ks = 0; ks < 8; ++ks) {
            acc0 = __builtin_amdgcn_mfma_f32_16x16x32_f16(A[ks], bw0[ks], acc0, 0, 0, 0);
            acc1 = __builtin_amdgcn_mfma_f32_16x16x32_f16(A[ks], bw1[ks], acc1, 0, 0, 0);
            f16x8 b2 = *(const f16x8*)&Bsh[(ks * 64 + lane) * 8];
            acc2 = __builtin_amdgcn_mfma_f32_16x16x32_f16(A[ks], b2, acc2, 0, 0, 0);
        }
        asm volatile("s_waitcnt vmcnt(16)" ::: "memory");
        __builtin_amdgcn_sched_barrier(0);
#pragma unroll
        for (int ks = 8; ks < 16; ++ks) {
            acc0 = __builtin_amdgcn_mfma_f32_16x16x32_f16(A[ks], bw0[ks], acc0, 0, 0, 0);
            acc1 = __builtin_amdgcn_mfma_f32_16x16x32_f16(A[ks], bw1[ks], acc1, 0, 0, 0);
            f16x8 b2 = *(const f16x8*)&Bsh[(ks * 64 + lane) * 8];
            acc2 = __builtin_amdgcn_mfma_f32_16x16x32_f16(A[ks], b2, acc2, 0, 0, 0);
        }
        asm volatile("s_waitcnt vmcnt(8)" ::: "memory");
        __builtin_amdgcn_sched_barrier(0);
#pragma unroll
        for (int ks = 16; ks < 24; ++ks) {
            acc0 = __builtin_amdgcn_mfma_f32_16x16x32_f16(A[ks], bw0[ks], acc0, 0, 0, 0);
            acc1 = __builtin_amdgcn_mfma_f32_16x16x32_f16(A[ks], bw1[ks], acc1, 0, 0, 0);
            f16x8 b2 = *(const f16x8*)&Bsh[(ks * 64 + lane) * 8];
            acc2 = __builtin_amdgcn_mfma_f32_16x16x32_f16(A[ks], b2, acc2, 0, 0, 0);
        }
        asm volatile("s_waitcnt vmcnt(0)" ::: "memory");
        __builtin_amdgcn_sched_barrier(0);
#pragma unroll
        for (int ks = 24; ks < 32; ++ks) {
            acc0 = __builtin_amdgcn_mfma_f32_16x16x32_f16(A[ks], bw0[ks], acc0, 0, 0, 0);
            acc1 = __builtin_amdgcn_mfma_f32_16x16x32_f16(A[ks], bw1[ks], acc1, 0, 0, 0);
            f16x8 b2 = *(const f16x8*)&Bsh[(ks * 64 + lane) * 8];
            acc2 = __builtin_amdgcn_mfma_f32_16x16x32_f16(A[ks], b2, acc2, 0, 0, 0);
        }

        // ---- gates + h update; pair-pack into per-wave LDS transpose ----
#pragma unroll
        for (int r = 0; r < 4; ++r) {
            float rg = fast_sigmoid(xr[r] + acc0[r] + bh_r);
            float zg = fast_sigmoid(xz[r] + acc1[r] + bh_z);
            float ng = fast_tanh(xn[r] + rg * (acc2[r] + bh_n));
            float hnew = (1.f - zg) * ng + zg * hp[r];
            hp[r] = hnew;
            float hx = __shfl_xor(hnew, 1);
            if (!(lane & 1)) {
                union { f16 h[2]; uint32_t u; } pk;
                pk.h[0] = (f16)hnew; pk.h[1] = (f16)hx;
                int row16 = ((lane >> 4) << 2) + r;
                TL32[wave][row16 * 10 + ((lane & 15) >> 1)] = pk.u;
            }
        }
        asm volatile("s_waitcnt lgkmcnt(0)" ::: "memory");
        __builtin_amdgcn_sched_barrier(0);

        // ---- ONE contiguous 8-B store per lane (512 B/wave) ----
        {
            u32x2 v2 = *(const u32x2*)&TL32[wave][p_row16 * 10 + p_qcol * 2];
            const char* gp = (const char*)hA + (size_t)(cur ^ 1) * 131072 + p_off;
            asm volatile("global_store_dwordx2 %0, %1, off sc0 sc1"
                         :: "v"(gp), "v"(v2) : "memory");
        }

        if (t == T_STEPS - 1) {
#pragma unroll
            for (int r = 0; r < 4; ++r)
                __builtin_nontemporal_store(hp[r],
                    &out[((size_t)t * BATCH + brow + r) * 1024 + j0 + col]);
            break;
        }

        // ---- per-wave drain + flag (no block barrier on producer side) ----
        asm volatile("s_waitcnt vmcnt(0)" ::: "memory");
        unsigned tgt = (unsigned)(t + 1);
        if (lane == 0)
            __hip_atomic_store(&flags[blk * 4 + wave], tgt,
                               __ATOMIC_RELAXED, __HIP_MEMORY_SCOPE_AGENT);

        // ---- off-critical-path: NT out stores + NT xproj prefetch ----
#pragma unroll
        for (int r = 0; r < 4; ++r)
            __builtin_nontemporal_store(hp[r],
                &out[((size_t)t * BATCH + brow + r) * 1024 + j0 + col]);
#pragma unroll
        for (int r = 0; r < 4; ++r) {
            size_t xb = ((size_t)(t + 1) * BATCH + brow + r) * NGATE + j0 + col;
            xr[r] = (float)__builtin_nontemporal_load(&xproj[xb]);
            xz[r] = (float)__builtin_nontemporal_load(&xproj[xb + 1024]);
            xn[r] = (float)__builtin_nontemporal_load(&xproj[xb + 2048]);
        }

        // ---- wave 0 polls all 256 wave-flags with ONE dwordx4 ----
        if (wave == 0) {
            const char* fptr = (const char*)flags + (size_t)lane * 16;
            for (;;) {
                u32x4 fv;
                asm volatile("global_load_dwordx4 %0, %1, off sc0 sc1\n\t"
                             "s_waitcnt vmcnt(0)"
                             : "=v"(fv) : "v"(fptr) : "memory");
                int ok = (fv[0] >= tgt) && (fv[1] >= tgt) && (fv[2] >= tgt) && (fv[3] >= tgt);
                if (__all(ok)) break;
            }
        }
        __syncthreads();
        cur ^= 1;
    }
}

// ---------------- launcher ----------------

extern "C" void kernel_launch(void* const* d_in, const int* in_sizes, int n_in,
                              void* d_out, int out_size, void* d_ws, size_t ws_size,
                              hipStream_t stream) {
    const float* x   = (const float*)d_in[0];   // [512,64,1024]
    const float* h0  = (const float*)d_in[1];   // [1,64,1024]
    const float* wih = (const float*)d_in[2];   // [3072,1024]
    const float* whh = (const float*)d_in[3];   // [3072,1024]
    const float* bih = (const float*)d_in[4];   // [3072]
    const float* bhh = (const float*)d_in[5];   // [3072]
    float* out = (float*)d_out;

    char* ws = (char*)d_ws;
    f16*      xf16  = (f16*)(ws + OFF_XF16);
    f16*      wihf  = (f16*)(ws + OFF_WIH);
    f16*      whhf  = (f16*)(ws + OFF_WHH);
    f16*      xproj = (f16*)(ws + OFF_XPROJ);
    f16*      hA    = (f16*)(ws + OFF_HA);
    unsigned* bar   = (unsigned*)(ws + OFF_BAR);

    init_misc<<<256, 256, 0, stream>>>(h0, hA, bar);
    cvt_f16<<<2048, 256, 0, stream>>>(x,   xf16, 33554432 / 4);
    cvt_f16<<<512,  256, 0, stream>>>(wih, wihf, 3145728 / 4);
    cvt_f16<<<512,  256, 0, stream>>>(whh, whhf, 3145728 / 4);
    gemm_xproj<<<6144, 256, 0, stream>>>(xf16, wihf, bih, xproj);
    gru_scan<<<64, 256, 0, stream>>>(xproj, whhf, bhh, h0, hA, out, bar);
}

// Round 7
// 2749.806 us; speedup vs baseline: 1.0931x; 1.0931x over previous
//
#include <hip/hip_runtime.h>
#include <hip/hip_bf16.h>
#include <stdint.h>
#include <stddef.h>

typedef _Float16 f16;
typedef __attribute__((ext_vector_type(8))) _Float16 f16x8;
typedef __attribute__((ext_vector_type(4))) _Float16 f16x4;
typedef __attribute__((ext_vector_type(4))) float f32x4;
typedef __attribute__((ext_vector_type(4))) uint32_t u32x4;

// Problem constants
#define T_STEPS 512
#define BATCH   64
#define KDIM    1024     // I == H == 1024
#define NGATE   3072     // 3*H

// Workspace layout (bytes), all 256-aligned
// NOTE: the h ring ALIASES the xf16 region — xf16 is fully consumed by
// gemm_xproj before gru_scan starts. 512 slots x 131072 B = 67108864 B.
#define OFF_XF16   0L            // x as f16 / h ring (aliased)
#define OFF_WIH    67108864L     // w_ih f16
#define OFF_WHH    73400320L     // w_hh f16
#define OFF_XPROJ  79691776L     // x_proj f16: 32768*3072*2
#define OFF_HINIT  281018368L    // h0 in fragment layout: 131072 B
#define OFF_BAR    281280512L    // 64 flag dwords

__device__ __forceinline__ void gload_lds16(const void* g, void* l) {
    __builtin_amdgcn_global_load_lds((__attribute__((address_space(1))) void*)g,
                                     (__attribute__((address_space(3))) void*)l,
                                     16, 0, 0);
}

// fragment index of h element (row, col):
//   chunk = ((row>>4)*32 + (col>>5))*64 + ((col>>3)&3)*16 + (row&15), elem = col&7
__device__ __forceinline__ int frag_idx(int row, int col) {
    return ((((row >> 4) * 32 + (col >> 5)) * 64 + ((col >> 3) & 3) * 16 + (row & 15)) << 3)
           + (col & 7);
}

// fast activations: v_exp/v_rcp based, endpoint-safe
__device__ __forceinline__ float fast_sigmoid(float x) {
    return __builtin_amdgcn_rcpf(1.f + __expf(-x));
}
__device__ __forceinline__ float fast_tanh(float x) {
    return 1.f - 2.f * __builtin_amdgcn_rcpf(1.f + __expf(2.f * x));
}

// ---------------- prep kernels ----------------

__global__ void init_misc(const float* __restrict__ h0,
                          f16* __restrict__ hinit, unsigned* __restrict__ bar) {
    if (blockIdx.x == 0 && threadIdx.x < 64) bar[threadIdx.x] = 0u;
    int i = blockIdx.x * 256 + threadIdx.x;       // 256 blocks -> exactly 65536 threads
    int row = i >> 10, col = i & 1023;
    hinit[frag_idx(row, col)] = (_Float16)h0[i];
}

__global__ void cvt_f16(const float* __restrict__ src, f16* __restrict__ dst, int n4) {
    int i = blockIdx.x * blockDim.x + threadIdx.x;
    int stride = gridDim.x * blockDim.x;
    for (; i < n4; i += stride) {
        float4 v = ((const float4*)src)[i];
        f16x4 o = { (_Float16)v.x, (_Float16)v.y, (_Float16)v.z, (_Float16)v.w };
        *(f16x4*)&dst[(size_t)i * 4] = o;
    }
}

// ---------------- x-projection GEMM ----------------

__global__ __launch_bounds__(256) void gemm_xproj(const f16* __restrict__ A,
                                                  const f16* __restrict__ Bt,
                                                  const float* __restrict__ bias,
                                                  f16* __restrict__ C) {
    __shared__ f16 As[128 * 32];
    __shared__ f16 Bs[128 * 32];
    const int K = KDIM;
    int bm = blockIdx.x / 24, bn = blockIdx.x % 24;
    int m0 = bm * 128, n0 = bn * 128;
    int tid = threadIdx.x, wave = tid >> 6, lane = tid & 63;
    int wm = wave >> 1, wn = wave & 1;

    f32x4 acc[4][4];
#pragma unroll
    for (int i = 0; i < 4; i++)
#pragma unroll
        for (int j = 0; j < 4; j++) acc[i][j] = (f32x4){0.f, 0.f, 0.f, 0.f};

    int srow = lane >> 2;
    int kc = lane & 3;

    for (int k0 = 0; k0 < K; k0 += 32) {
#pragma unroll
        for (int s = 0; s < 2; ++s) {
            int seg = wave * 2 + s;
            int row = seg * 16 + srow;
            gload_lds16(&A[(size_t)(m0 + row) * K + k0 + kc * 8], &As[seg * 512]);
            gload_lds16(&Bt[(size_t)(n0 + row) * K + k0 + kc * 8], &Bs[seg * 512]);
        }
        __syncthreads();

        f16x8 af[4], bfg[4];
#pragma unroll
        for (int i = 0; i < 4; i++) {
            af[i]  = *(const f16x8*)&As[(wm * 64 + i * 16 + (lane & 15)) * 32 + (lane >> 4) * 8];
            bfg[i] = *(const f16x8*)&Bs[(wn * 64 + i * 16 + (lane & 15)) * 32 + (lane >> 4) * 8];
        }
#pragma unroll
        for (int i = 0; i < 4; i++)
#pragma unroll
            for (int j = 0; j < 4; j++)
                acc[i][j] = __builtin_amdgcn_mfma_f32_16x16x32_f16(af[i], bfg[j], acc[i][j], 0, 0, 0);
        __syncthreads();
    }

#pragma unroll
    for (int j = 0; j < 4; j++) {
        int col = n0 + wn * 64 + j * 16 + (lane & 15);
        float bv = bias[col];
#pragma unroll
        for (int i = 0; i < 4; i++) {
            int rbase = m0 + wm * 64 + i * 16 + (lane >> 4) * 4;
#pragma unroll
            for (int r = 0; r < 4; r++)
                C[(size_t)(rbase + r) * NGATE + col] = (_Float16)(acc[i][j][r] + bv);
        }
    }
}

// ---------------- persistent GRU scan ----------------
// 64 blocks x 256 threads (1 block/CU). Block p owns hidden cols [16p, 16p+16).
// h ring: one FRESH 128 KB slot per step (never-cached addresses), so
// consumer h loads are PLAIN L2-cached: first block per XCD pulls each line
// from MALL (MSHR-merged), the other 7 blocks hit the shared per-XCD L2.
// Producer h stores are sc0 sc1 (write to MALL), drained before the flag.
// Block-level flag barrier: wave 0 polls, other waves park at __syncthreads.

__global__ __launch_bounds__(256, 1) void gru_scan(const f16* __restrict__ xproj,
                                                   const f16* __restrict__ whh16,
                                                   const float* __restrict__ bhh,
                                                   const float* __restrict__ h0,
                                                   const f16* __restrict__ hinit,
                                                   f16* __restrict__ ring,
                                                   float* __restrict__ out,
                                                   unsigned* __restrict__ flags) {
    __shared__ f16 Bsh[32 * 64 * 8];   // gate-n B-fragments, 32 KiB

    const int tid = threadIdx.x, wave = tid >> 6, lane = tid & 63;
    const int blk = blockIdx.x;
    const int j0 = blk * 16;
    const int col = lane & 15;
    const int kofs = (lane >> 4) * 8;

    // stage gate-n B-fragments into LDS
    for (int c = tid; c < 2048; c += 256) {
        int ks = c >> 6, l = c & 63;
        int row = 2048 + j0 + (l & 15);
        int kk = ks * 32 + ((l >> 4) * 8);
        *(f16x8*)&Bsh[c * 8] = *(const f16x8*)&whh16[(size_t)row * 1024 + kk];
    }

    // gates r,z B-fragments in registers
    f16x8 bw0[32], bw1[32];
#pragma unroll
    for (int ks = 0; ks < 32; ++ks) {
        bw0[ks] = *(const f16x8*)&whh16[(size_t)(j0 + col) * 1024 + ks * 32 + kofs];
        bw1[ks] = *(const f16x8*)&whh16[(size_t)(1024 + j0 + col) * 1024 + ks * 32 + kofs];
    }

    const float bh_r = bhh[j0 + col];
    const float bh_z = bhh[1024 + j0 + col];
    const float bh_n = bhh[2048 + j0 + col];

    const int brow = wave * 16 + ((lane >> 4) << 2);   // C/D row base
    float hp[4];
#pragma unroll
    for (int r = 0; r < 4; ++r) hp[r] = h0[(size_t)(brow + r) * 1024 + j0 + col];

    // h-fragment store addressing (even lanes store packed pairs)
    const int ksb = blk >> 1;
    const int lh  = ((blk & 1) << 1) | (col >> 3);

    __syncthreads();

    // xproj prefetch for t=0
    float xr[4], xz[4], xn[4];
#pragma unroll
    for (int r = 0; r < 4; ++r) {
        size_t xb = ((size_t)0 * BATCH + brow + r) * NGATE + j0 + col;
        xr[r] = (float)__builtin_nontemporal_load(&xproj[xb]);
        xz[r] = (float)__builtin_nontemporal_load(&xproj[xb + 1024]);
        xn[r] = (float)__builtin_nontemporal_load(&xproj[xb + 2048]);
    }

    const char* hsrc = (const char*)hinit;   // fragment-layout source for step t

#pragma unroll 1
    for (int t = 0; t < T_STEPS; ++t) {
        // ---- batched A-fragment loads (32 x 16B/lane, PLAIN cached) ----
        const char* hb = hsrc + (size_t)wave * 32768 + (size_t)lane * 16;
        f16x8 A[32];
#define HLOAD4(g4)                                                              \
        { const char* bp = hb + (g4) * 4096;                                    \
          asm volatile("global_load_dwordx4 %0, %4, off\n\t"                    \
                       "global_load_dwordx4 %1, %4, off offset:1024\n\t"        \
                       "global_load_dwordx4 %2, %4, off offset:2048\n\t"        \
                       "global_load_dwordx4 %3, %4, off offset:3072"            \
                       : "=&v"(A[(g4)*4]), "=&v"(A[(g4)*4+1]),                  \
                         "=&v"(A[(g4)*4+2]), "=&v"(A[(g4)*4+3])                 \
                       : "v"(bp)); }
        HLOAD4(0) HLOAD4(1) HLOAD4(2) HLOAD4(3)
        HLOAD4(4) HLOAD4(5) HLOAD4(6) HLOAD4(7)
#undef HLOAD4
        asm volatile("s_waitcnt vmcnt(0)" ::: "memory");
        __builtin_amdgcn_sched_barrier(0);

        // ---- MFMA: 3 gates x 32 k-slices ----
        f32x4 acc0 = {0.f,0.f,0.f,0.f}, acc1 = {0.f,0.f,0.f,0.f}, acc2 = {0.f,0.f,0.f,0.f};
#pragma unroll
        for (int ks = 0; ks < 32; ++ks) {
            acc0 = __builtin_amdgcn_mfma_f32_16x16x32_f16(A[ks], bw0[ks], acc0, 0, 0, 0);
            acc1 = __builtin_amdgcn_mfma_f32_16x16x32_f16(A[ks], bw1[ks], acc1, 0, 0, 0);
            f16x8 b2 = *(const f16x8*)&Bsh[(ks * 64 + lane) * 8];
            acc2 = __builtin_amdgcn_mfma_f32_16x16x32_f16(A[ks], b2, acc2, 0, 0, 0);
        }

        // ---- gates + h update + fragment-layout h stores (fresh ring slot) ----
        f16* hdst = ring + (size_t)t * 65536;
#pragma unroll
        for (int r = 0; r < 4; ++r) {
            float rg = fast_sigmoid(xr[r] + acc0[r] + bh_r);
            float zg = fast_sigmoid(xz[r] + acc1[r] + bh_z);
            float ng = fast_tanh(xn[r] + rg * (acc2[r] + bh_n));
            float hnew = (1.f - zg) * ng + zg * hp[r];
            hp[r] = hnew;
            float hx = __shfl_xor(hnew, 1);
            if (!(lane & 1)) {
                union { f16 h[2]; uint32_t u; } pk;
                pk.h[0] = (f16)hnew; pk.h[1] = (f16)hx;
                int fi = (((wave * 32 + ksb) * 64 + lh * 16 + ((lane >> 4) << 2) + r) << 3)
                         + (lane & 7);
                __hip_atomic_store((uint32_t*)&hdst[fi], pk.u,
                                   __ATOMIC_RELAXED, __HIP_MEMORY_SCOPE_AGENT);
            }
        }

        if (t == T_STEPS - 1) {
#pragma unroll
            for (int r = 0; r < 4; ++r)
                __builtin_nontemporal_store(hp[r],
                    &out[((size_t)t * BATCH + brow + r) * 1024 + j0 + col]);
            break;
        }

        // ---- signal: drain h stores (all waves at barrier), one lane flags ----
        __syncthreads();
        unsigned tgt = (unsigned)(t + 1);
        if (tid == 0)
            __hip_atomic_store(&flags[blk], tgt, __ATOMIC_RELAXED, __HIP_MEMORY_SCOPE_AGENT);

        // ---- off-critical-path: NT out stores + NT xproj prefetch ----
#pragma unroll
        for (int r = 0; r < 4; ++r)
            __builtin_nontemporal_store(hp[r],
                &out[((size_t)t * BATCH + brow + r) * 1024 + j0 + col]);
#pragma unroll
        for (int r = 0; r < 4; ++r) {
            size_t xb = ((size_t)(t + 1) * BATCH + brow + r) * NGATE + j0 + col;
            xr[r] = (float)__builtin_nontemporal_load(&xproj[xb]);
            xz[r] = (float)__builtin_nontemporal_load(&xproj[xb + 1024]);
            xn[r] = (float)__builtin_nontemporal_load(&xproj[xb + 2048]);
        }

        // ---- wave 0 polls; other waves park at the barrier ----
        if (wave == 0) {
            for (;;) {
                unsigned v = __hip_atomic_load(&flags[lane], __ATOMIC_RELAXED,
                                               __HIP_MEMORY_SCOPE_AGENT);
                if (__all((int)(v >= tgt))) break;
            }
        }
        __syncthreads();
        asm volatile("" ::: "memory");
        hsrc = (const char*)(ring + (size_t)t * 65536);
    }
}

// ---------------- launcher ----------------

extern "C" void kernel_launch(void* const* d_in, const int* in_sizes, int n_in,
                              void* d_out, int out_size, void* d_ws, size_t ws_size,
                              hipStream_t stream) {
    const float* x   = (const float*)d_in[0];   // [512,64,1024]
    const float* h0  = (const float*)d_in[1];   // [1,64,1024]
    const float* wih = (const float*)d_in[2];   // [3072,1024]
    const float* whh = (const float*)d_in[3];   // [3072,1024]
    const float* bih = (const float*)d_in[4];   // [3072]
    const float* bhh = (const float*)d_in[5];   // [3072]
    float* out = (float*)d_out;

    char* ws = (char*)d_ws;
    f16*      xf16  = (f16*)(ws + OFF_XF16);    // aliased: h ring after gemm
    f16*      wihf  = (f16*)(ws + OFF_WIH);
    f16*      whhf  = (f16*)(ws + OFF_WHH);
    f16*      xproj = (f16*)(ws + OFF_XPROJ);
    f16*      hinit = (f16*)(ws + OFF_HINIT);
    unsigned* bar   = (unsigned*)(ws + OFF_BAR);

    init_misc<<<256, 256, 0, stream>>>(h0, hinit, bar);
    cvt_f16<<<2048, 256, 0, stream>>>(x,   xf16, 33554432 / 4);
    cvt_f16<<<512,  256, 0, stream>>>(wih, wihf, 3145728 / 4);
    cvt_f16<<<512,  256, 0, stream>>>(whh, whhf, 3145728 / 4);
    gemm_xproj<<<6144, 256, 0, stream>>>(xf16, wihf, bih, xproj);
    gru_scan<<<64, 256, 0, stream>>>(xproj, whhf, bhh, h0, hinit, xf16, out, bar);
}

// Round 10
// 2449.555 us; speedup vs baseline: 1.2270x; 1.1226x over previous
//
#include <hip/hip_runtime.h>
#include <hip/hip_bf16.h>
#include <stdint.h>
#include <stddef.h>

typedef _Float16 f16;
typedef __attribute__((ext_vector_type(8))) _Float16 f16x8;
typedef __attribute__((ext_vector_type(4))) _Float16 f16x4;
typedef __attribute__((ext_vector_type(4))) float f32x4;
typedef __attribute__((ext_vector_type(4))) uint32_t u32x4;

// Problem constants
#define T_STEPS 512
#define BATCH   64
#define KDIM    1024     // I == H == 1024
#define NGATE   3072     // 3*H

// Workspace layout (bytes)
// h ring ALIASES xf16 (consumed by gemm before the scan): 512 slots x 131072 B.
#define OFF_XF16   0L            // x as f16 / h ring (aliased)
#define OFF_WIH    67108864L     // w_ih f16
#define OFF_WHH    73400320L     // w_hh f16
#define OFF_XPROJ  79691776L     // x_proj f16: 32768*3072*2
#define OFF_HINIT  281018368L    // h0 in fragment layout: 131072 B
#define OFF_BAR    281280512L    // 64 flag dwords
#define SLOT_BYTES 131072L

__device__ __forceinline__ void gload_lds16(const void* g, void* l) {
    __builtin_amdgcn_global_load_lds((__attribute__((address_space(1))) void*)g,
                                     (__attribute__((address_space(3))) void*)l,
                                     16, 0, 0);
}

// fragment index of h element (row, col):
//   chunk = ((row>>4)*32 + (col>>5))*64 + ((col>>3)&3)*16 + (row&15), elem = col&7
__device__ __forceinline__ int frag_idx(int row, int col) {
    return ((((row >> 4) * 32 + (col >> 5)) * 64 + ((col >> 3) & 3) * 16 + (row & 15)) << 3)
           + (col & 7);
}

// fast activations: v_exp/v_rcp based, endpoint-safe
__device__ __forceinline__ float fast_sigmoid(float x) {
    return __builtin_amdgcn_rcpf(1.f + __expf(-x));
}
__device__ __forceinline__ float fast_tanh(float x) {
    return 1.f - 2.f * __builtin_amdgcn_rcpf(1.f + __expf(2.f * x));
}

// ---------------- prep kernels ----------------

__global__ void init_misc(const float* __restrict__ h0,
                          f16* __restrict__ hinit, unsigned* __restrict__ bar) {
    if (blockIdx.x == 0 && threadIdx.x < 64) bar[threadIdx.x] = 0u;
    int i = blockIdx.x * 256 + threadIdx.x;       // 256 blocks -> exactly 65536 threads
    int row = i >> 10, col = i & 1023;
    hinit[frag_idx(row, col)] = (_Float16)h0[i];
}

__global__ void cvt_f16(const float* __restrict__ src, f16* __restrict__ dst, int n4) {
    int i = blockIdx.x * blockDim.x + threadIdx.x;
    int stride = gridDim.x * blockDim.x;
    for (; i < n4; i += stride) {
        float4 v = ((const float4*)src)[i];
        f16x4 o = { (_Float16)v.x, (_Float16)v.y, (_Float16)v.z, (_Float16)v.w };
        *(f16x4*)&dst[(size_t)i * 4] = o;
    }
}

// ---------------- x-projection GEMM ----------------

__global__ __launch_bounds__(256) void gemm_xproj(const f16* __restrict__ A,
                                                  const f16* __restrict__ Bt,
                                                  const float* __restrict__ bias,
                                                  f16* __restrict__ C) {
    __shared__ f16 As[128 * 32];
    __shared__ f16 Bs[128 * 32];
    const int K = KDIM;
    int bm = blockIdx.x / 24, bn = blockIdx.x % 24;
    int m0 = bm * 128, n0 = bn * 128;
    int tid = threadIdx.x, wave = tid >> 6, lane = tid & 63;
    int wm = wave >> 1, wn = wave & 1;

    f32x4 acc[4][4];
#pragma unroll
    for (int i = 0; i < 4; i++)
#pragma unroll
        for (int j = 0; j < 4; j++) acc[i][j] = (f32x4){0.f, 0.f, 0.f, 0.f};

    int srow = lane >> 2;
    int kc = lane & 3;

    for (int k0 = 0; k0 < K; k0 += 32) {
#pragma unroll
        for (int s = 0; s < 2; ++s) {
            int seg = wave * 2 + s;
            int row = seg * 16 + srow;
            gload_lds16(&A[(size_t)(m0 + row) * K + k0 + kc * 8], &As[seg * 512]);
            gload_lds16(&Bt[(size_t)(n0 + row) * K + k0 + kc * 8], &Bs[seg * 512]);
        }
        __syncthreads();

        f16x8 af[4], bfg[4];
#pragma unroll
        for (int i = 0; i < 4; i++) {
            af[i]  = *(const f16x8*)&As[(wm * 64 + i * 16 + (lane & 15)) * 32 + (lane >> 4) * 8];
            bfg[i] = *(const f16x8*)&Bs[(wn * 64 + i * 16 + (lane & 15)) * 32 + (lane >> 4) * 8];
        }
#pragma unroll
        for (int i = 0; i < 4; i++)
#pragma unroll
            for (int j = 0; j < 4; j++)
                acc[i][j] = __builtin_amdgcn_mfma_f32_16x16x32_f16(af[i], bfg[j], acc[i][j], 0, 0, 0);
        __syncthreads();
    }

#pragma unroll
    for (int j = 0; j < 4; j++) {
        int col = n0 + wn * 64 + j * 16 + (lane & 15);
        float bv = bias[col];
#pragma unroll
        for (int i = 0; i < 4; i++) {
            int rbase = m0 + wm * 64 + i * 16 + (lane >> 4) * 4;
#pragma unroll
            for (int r = 0; r < 4; r++)
                C[(size_t)(rbase + r) * NGATE + col] = (_Float16)(acc[i][j][r] + bv);
        }
    }
}

// ---------------- persistent GRU scan ----------------
// 64 blocks x 256 threads (1 block/CU). Block p owns hidden cols [16p, 16p+16).
// h ring: one FRESH 128 KB slot per step (never-cached addresses), so
// consumer h loads are PLAIN L2-cached. Producer h stores are sc0 sc1
// (write to MALL), drained by the pre-flag __syncthreads.
// Block-level flag barrier: wave 0 polls, other waves park at __syncthreads.
// NEW vs R7: staged vmcnt(24/16/8/0) so MFMA group g overlaps the load tail
// of groups g+1.. (correct for any wave: at h-load issue each wave has <=16
// older vmem ops outstanding, and vmem retires in issue order, so
// vmcnt(24) => >=8 oldest h-loads retired). 6 accumulator chains (parity
// split per gate) keep the MFMA stream dependency-free.

__global__ __launch_bounds__(256, 1) void gru_scan(const f16* __restrict__ xproj,
                                                   const f16* __restrict__ whh16,
                                                   const float* __restrict__ bhh,
                                                   const float* __restrict__ h0,
                                                   const f16* __restrict__ hinit,
                                                   f16* __restrict__ ring,
                                                   float* __restrict__ out,
                                                   unsigned* __restrict__ flags) {
    __shared__ f16 Bsh[32 * 64 * 8];   // gate-n B-fragments, 32 KiB

    const int tid = threadIdx.x, wave = tid >> 6, lane = tid & 63;
    const int blk = blockIdx.x;
    const int j0 = blk * 16;
    const int col = lane & 15;
    const int kofs = (lane >> 4) * 8;

    // stage gate-n B-fragments into LDS
    for (int c = tid; c < 2048; c += 256) {
        int ks = c >> 6, l = c & 63;
        int row = 2048 + j0 + (l & 15);
        int kk = ks * 32 + ((l >> 4) * 8);
        *(f16x8*)&Bsh[c * 8] = *(const f16x8*)&whh16[(size_t)row * 1024 + kk];
    }

    // gates r,z B-fragments in registers
    f16x8 bw0[32], bw1[32];
#pragma unroll
    for (int ks = 0; ks < 32; ++ks) {
        bw0[ks] = *(const f16x8*)&whh16[(size_t)(j0 + col) * 1024 + ks * 32 + kofs];
        bw1[ks] = *(const f16x8*)&whh16[(size_t)(1024 + j0 + col) * 1024 + ks * 32 + kofs];
    }

    const float bh_r = bhh[j0 + col];
    const float bh_z = bhh[1024 + j0 + col];
    const float bh_n = bhh[2048 + j0 + col];

    const int brow = wave * 16 + ((lane >> 4) << 2);   // C/D row base
    float hp[4];
#pragma unroll
    for (int r = 0; r < 4; ++r) hp[r] = h0[(size_t)(brow + r) * 1024 + j0 + col];

    // h-fragment store addressing (even lanes store packed pairs)
    const int ksb = blk >> 1;
    const int lh  = ((blk & 1) << 1) | (col >> 3);

    __syncthreads();

    // xproj prefetch for t=0
    float xr[4], xz[4], xn[4];
#pragma unroll
    for (int r = 0; r < 4; ++r) {
        size_t xb = ((size_t)0 * BATCH + brow + r) * NGATE + j0 + col;
        xr[r] = (float)__builtin_nontemporal_load(&xproj[xb]);
        xz[r] = (float)__builtin_nontemporal_load(&xproj[xb + 1024]);
        xn[r] = (float)__builtin_nontemporal_load(&xproj[xb + 2048]);
    }

    const char* hsrc = (const char*)hinit;   // fragment-layout source for step t

#pragma unroll 1
    for (int t = 0; t < T_STEPS; ++t) {
        // ---- batched A-fragment loads (32 x 16B/lane, PLAIN cached) ----
        const char* hb = hsrc + (size_t)wave * 32768 + (size_t)lane * 16;
        f16x8 A[32];
#define HLOAD4(g4)                                                              \
        { const char* bp = hb + (g4) * 4096;                                    \
          asm volatile("global_load_dwordx4 %0, %4, off\n\t"                    \
                       "global_load_dwordx4 %1, %4, off offset:1024\n\t"        \
                       "global_load_dwordx4 %2, %4, off offset:2048\n\t"        \
                       "global_load_dwordx4 %3, %4, off offset:3072"            \
                       : "=&v"(A[(g4)*4]), "=&v"(A[(g4)*4+1]),                  \
                         "=&v"(A[(g4)*4+2]), "=&v"(A[(g4)*4+3])                 \
                       : "v"(bp)); }
        HLOAD4(0) HLOAD4(1) HLOAD4(2) HLOAD4(3)
        HLOAD4(4) HLOAD4(5) HLOAD4(6) HLOAD4(7)
#undef HLOAD4

        // ---- MFMA: 4 staged groups x (8 ks x 3 gates), 6 acc chains ----
        f32x4 a0a = {0.f,0.f,0.f,0.f}, a0b = {0.f,0.f,0.f,0.f};
        f32x4 a1a = {0.f,0.f,0.f,0.f}, a1b = {0.f,0.f,0.f,0.f};
        f32x4 a2a = {0.f,0.f,0.f,0.f}, a2b = {0.f,0.f,0.f,0.f};

#define MFMA_GROUP(G)                                                           \
        _Pragma("unroll")                                                       \
        for (int ks = (G) * 8; ks < (G) * 8 + 8; ++ks) {                        \
            f16x8 b2 = *(const f16x8*)&Bsh[(ks * 64 + lane) * 8];               \
            if (ks & 1) {                                                       \
                a0b = __builtin_amdgcn_mfma_f32_16x16x32_f16(A[ks], bw0[ks], a0b, 0, 0, 0); \
                a1b = __builtin_amdgcn_mfma_f32_16x16x32_f16(A[ks], bw1[ks], a1b, 0, 0, 0); \
                a2b = __builtin_amdgcn_mfma_f32_16x16x32_f16(A[ks], b2,      a2b, 0, 0, 0); \
            } else {                                                            \
                a0a = __builtin_amdgcn_mfma_f32_16x16x32_f16(A[ks], bw0[ks], a0a, 0, 0, 0); \
                a1a = __builtin_amdgcn_mfma_f32_16x16x32_f16(A[ks], bw1[ks], a1a, 0, 0, 0); \
                a2a = __builtin_amdgcn_mfma_f32_16x16x32_f16(A[ks], b2,      a2a, 0, 0, 0); \
            }                                                                   \
        }

        asm volatile("s_waitcnt vmcnt(24)" ::: "memory");
        __builtin_amdgcn_sched_barrier(0);
        MFMA_GROUP(0)
        asm volatile("s_waitcnt vmcnt(16)" ::: "memory");
        __builtin_amdgcn_sched_barrier(0);
        MFMA_GROUP(1)
        asm volatile("s_waitcnt vmcnt(8)" ::: "memory");
        __builtin_amdgcn_sched_barrier(0);
        MFMA_GROUP(2)
        asm volatile("s_waitcnt vmcnt(0)" ::: "memory");
        __builtin_amdgcn_sched_barrier(0);
        MFMA_GROUP(3)
#undef MFMA_GROUP

        f32x4 acc0 = a0a + a0b, acc1 = a1a + a1b, acc2 = a2a + a2b;

        // ---- gates + h update + fragment-layout h stores (fresh ring slot) ----
        f16* hdst = ring + (size_t)t * 65536;
#pragma unroll
        for (int r = 0; r < 4; ++r) {
            float rg = fast_sigmoid(xr[r] + acc0[r] + bh_r);
            float zg = fast_sigmoid(xz[r] + acc1[r] + bh_z);
            float ng = fast_tanh(xn[r] + rg * (acc2[r] + bh_n));
            float hnew = (1.f - zg) * ng + zg * hp[r];
            hp[r] = hnew;
            float hx = __shfl_xor(hnew, 1);
            if (!(lane & 1)) {
                union { f16 h[2]; uint32_t u; } pk;
                pk.h[0] = (f16)hnew; pk.h[1] = (f16)hx;
                int fi = (((wave * 32 + ksb) * 64 + lh * 16 + ((lane >> 4) << 2) + r) << 3)
                         + (lane & 7);
                __hip_atomic_store((uint32_t*)&hdst[fi], pk.u,
                                   __ATOMIC_RELAXED, __HIP_MEMORY_SCOPE_AGENT);
            }
        }

        if (t == T_STEPS - 1) {
#pragma unroll
            for (int r = 0; r < 4; ++r)
                __builtin_nontemporal_store(hp[r],
                    &out[((size_t)t * BATCH + brow + r) * 1024 + j0 + col]);
            break;
        }

        // ---- signal: drain h stores (all waves at barrier), one lane flags ----
        __syncthreads();
        unsigned tgt = (unsigned)(t + 1);
        if (tid == 0)
            __hip_atomic_store(&flags[blk], tgt, __ATOMIC_RELAXED, __HIP_MEMORY_SCOPE_AGENT);

        // ---- off-critical-path: NT out stores + NT xproj prefetch ----
#pragma unroll
        for (int r = 0; r < 4; ++r)
            __builtin_nontemporal_store(hp[r],
                &out[((size_t)t * BATCH + brow + r) * 1024 + j0 + col]);
#pragma unroll
        for (int r = 0; r < 4; ++r) {
            size_t xb = ((size_t)(t + 1) * BATCH + brow + r) * NGATE + j0 + col;
            xr[r] = (float)__builtin_nontemporal_load(&xproj[xb]);
            xz[r] = (float)__builtin_nontemporal_load(&xproj[xb + 1024]);
            xn[r] = (float)__builtin_nontemporal_load(&xproj[xb + 2048]);
        }

        // ---- wave 0 polls; other waves park at the barrier ----
        if (wave == 0) {
            for (;;) {
                unsigned v = __hip_atomic_load(&flags[lane], __ATOMIC_RELAXED,
                                               __HIP_MEMORY_SCOPE_AGENT);
                if (__all((int)(v >= tgt))) break;
            }
        }
        __syncthreads();
        asm volatile("" ::: "memory");
        hsrc = (const char*)(ring + (size_t)t * 65536);
    }
}

// ---------------- launcher ----------------

extern "C" void kernel_launch(void* const* d_in, const int* in_sizes, int n_in,
                              void* d_out, int out_size, void* d_ws, size_t ws_size,
                              hipStream_t stream) {
    const float* x   = (const float*)d_in[0];   // [512,64,1024]
    const float* h0  = (const float*)d_in[1];   // [1,64,1024]
    const float* wih = (const float*)d_in[2];   // [3072,1024]
    const float* whh = (const float*)d_in[3];   // [3072,1024]
    const float* bih = (const float*)d_in[4];   // [3072]
    const float* bhh = (const float*)d_in[5];   // [3072]
    float* out = (float*)d_out;

    char* ws = (char*)d_ws;
    f16*      xf16  = (f16*)(ws + OFF_XF16);    // aliased: h ring after gemm
    f16*      wihf  = (f16*)(ws + OFF_WIH);
    f16*      whhf  = (f16*)(ws + OFF_WHH);
    f16*      xproj = (f16*)(ws + OFF_XPROJ);
    f16*      hinit = (f16*)(ws + OFF_HINIT);
    unsigned* bar   = (unsigned*)(ws + OFF_BAR);

    init_misc<<<256, 256, 0, stream>>>(h0, hinit, bar);
    cvt_f16<<<2048, 256, 0, stream>>>(x,   xf16, 33554432 / 4);
    cvt_f16<<<512,  256, 0, stream>>>(wih, wihf, 3145728 / 4);
    cvt_f16<<<512,  256, 0, stream>>>(whh, whhf, 3145728 / 4);
    gemm_xproj<<<6144, 256, 0, stream>>>(xf16, wihf, bih, xproj);
    gru_scan<<<64, 256, 0, stream>>>(xproj, whhf, bhh, h0, hinit, xf16, out, bar);
}